// Round 3
// baseline (94.421 us; speedup 1.0000x reference)
//
#include <hip/hip_runtime.h>
#include <hip/hip_bf16.h>

#define N 384
#define D 128
#define TAU 0.25f
#define MARGIN 0.5f

// ---------------- K1: fused normalize + Gram -> distance tiles ----------
// grid: 288 blocks (0-143: src tiles, 144-287: emb tiles) of 256 threads.
// Each block: (a) inv L2-norms of the 64 rows it touches, (b) stage
// normalized transposed 32x32 tiles in LDS, (c) 2x2 micro-tile GEMM,
// (d) src tiles write their tile-sum to tsum[t2] (no atomics).
__global__ __launch_bounds__(256) void k_gram(const float* __restrict__ xsrc,
                                              const float* __restrict__ xemb,
                                              float* __restrict__ dsrc,
                                              float* __restrict__ demb,
                                              float* __restrict__ tsum,
                                              float* __restrict__ accum) {
    __shared__ float At[D][34];
    __shared__ float Bt[D][34];
    __shared__ float inv_s[64];
    __shared__ float ps[4];
    int bid = blockIdx.x;
    int lin = threadIdx.x;
    if (bid == 0 && lin == 0) {              // zero reduction cells (ws is 0xAA-poisoned)
        accum[0] = 0.f; accum[1] = 0.f;
        ((unsigned int*)accum)[2] = 0u;
    }
    int mat = (bid >= 144) ? 1 : 0;
    int t2  = mat ? bid - 144 : bid;
    int bi = t2 / 12, bj = t2 % 12;
    const float* xn = mat ? xemb : xsrc;
    float* out      = mat ? demb : dsrc;

    // (a) row inv-norms: vrow 0..31 -> A rows, 32..63 -> B rows
    int wv = lin >> 6, lane = lin & 63;
    #pragma unroll
    for (int rr = 0; rr < 16; ++rr) {
        int vr = wv * 16 + rr;
        int r  = vr & 31;
        int grow = ((vr >> 5) ? bj : bi) * 32 + r;
        float2 v = ((const float2*)(xn + (size_t)grow * D))[lane];
        float ss = v.x * v.x + v.y * v.y;
        #pragma unroll
        for (int o = 32; o > 0; o >>= 1) ss += __shfl_xor(ss, o);
        if (lane == 0) inv_s[vr] = 1.0f / fmaxf(sqrtf(ss), 1e-12f);
    }
    __syncthreads();

    // (b) stage normalized, transposed (reads hit L1 from phase a)
    #pragma unroll
    for (int l = 0; l < 4; ++l) {
        int idx = lin + l * 256;
        int row = idx >> 5;        // 0..31
        int c4  = idx & 31;        // float4 index within row
        float ia = inv_s[row], ib = inv_s[32 + row];
        float4 va = ((const float4*)(xn + (size_t)(bi * 32 + row) * D))[c4];
        At[c4 * 4 + 0][row] = va.x * ia; At[c4 * 4 + 1][row] = va.y * ia;
        At[c4 * 4 + 2][row] = va.z * ia; At[c4 * 4 + 3][row] = va.w * ia;
        float4 vb = ((const float4*)(xn + (size_t)(bj * 32 + row) * D))[c4];
        Bt[c4 * 4 + 0][row] = vb.x * ib; Bt[c4 * 4 + 1][row] = vb.y * ib;
        Bt[c4 * 4 + 2][row] = vb.z * ib; Bt[c4 * 4 + 3][row] = vb.w * ib;
    }
    __syncthreads();

    // (c) 2x2 micro GEMM over K=128
    int tx = lin & 15, ty = lin >> 4;
    float a00 = 0.f, a01 = 0.f, a10 = 0.f, a11 = 0.f;
    #pragma unroll 8
    for (int k = 0; k < D; k++) {
        float x0 = At[k][2 * ty], x1 = At[k][2 * ty + 1];
        float y0 = Bt[k][2 * tx], y1 = Bt[k][2 * tx + 1];
        a00 = fmaf(x0, y0, a00); a01 = fmaf(x0, y1, a01);
        a10 = fmaf(x1, y0, a10); a11 = fmaf(x1, y1, a11);
    }
    float d00 = 1.f - a00, d01 = 1.f - a01, d10 = 1.f - a10, d11 = 1.f - a11;
    int r0 = bi * 32 + 2 * ty, c0 = bj * 32 + 2 * tx;
    out[(size_t)r0 * N + c0]           = d00;
    out[(size_t)r0 * N + c0 + 1]       = d01;
    out[(size_t)(r0 + 1) * N + c0]     = d10;
    out[(size_t)(r0 + 1) * N + c0 + 1] = d11;

    // (d) deterministic per-tile sum for the source-mean
    if (!mat) {
        float s = d00 + d01 + d10 + d11;
        #pragma unroll
        for (int o = 32; o > 0; o >>= 1) s += __shfl_xor(s, o);
        if ((lin & 63) == 0) ps[lin >> 6] = s;
        __syncthreads();
        if (lin == 0) tsum[t2] = ps[0] + ps[1] + ps[2] + ps[3];
    }
}

// ---------------- K2: weights-on-the-fly + semihard max + final ---------
// grid: N blocks of N threads, block i owns row i.
// mean from tsum (uniform scalar loads); wn row staged in LDS (1 exp per
// thread), k-loop = 1 broadcast ds_read_b128 per 4 iters + scalar der[k]
// stream; last block (ticket) computes the safe division into d_out.
__global__ __launch_bounds__(N) void k_main(const float* __restrict__ dsrc,
                                            const float* __restrict__ demb,
                                            const float* __restrict__ tsum,
                                            float* __restrict__ accum,
                                            float* __restrict__ out) {
    __shared__ float wn[N];
    __shared__ float pn[6], pd[6];
    int i = blockIdx.x;
    int t = threadIdx.x;
    float total = 0.f;
    #pragma unroll
    for (int j = 0; j < 144; ++j) total += tsum[j];
    float mean  = total * (1.0f / (float)(N * N));
    float scale = 1.0f / (fmaxf(mean, 1e-12f) * TAU);
    const float* dsr = dsrc + (size_t)i * N;
    const float* der = demb + (size_t)i * N;
    float w = expf(-dsr[t] * scale);     // teacher pos-weight for pair (i,t)
    wn[t] = 1.0f - w;
    float c = MARGIN + der[t];           // tl = c - de[k]
    __syncthreads();
    float m0 = 0.f, m1 = 0.f, m2 = 0.f, m3 = 0.f;
    #pragma unroll 2
    for (int k = 0; k < N; k += 4) {
        float4 wvk = *(const float4*)&wn[k];
        float d0 = der[k], d1 = der[k + 1], d2 = der[k + 2], d3 = der[k + 3];
        float tl0 = c - d0; float v0 = tl0 * wvk.x;
        v0 = (tl0 <= MARGIN) ? v0 : 0.f; m0 = fmaxf(m0, v0);
        float tl1 = c - d1; float v1 = tl1 * wvk.y;
        v1 = (tl1 <= MARGIN) ? v1 : 0.f; m1 = fmaxf(m1, v1);
        float tl2 = c - d2; float v2 = tl2 * wvk.z;
        v2 = (tl2 <= MARGIN) ? v2 : 0.f; m2 = fmaxf(m2, v2);
        float tl3 = c - d3; float v3 = tl3 * wvk.w;
        v3 = (tl3 <= MARGIN) ? v3 : 0.f; m3 = fmaxf(m3, v3);
    }
    float m = fmaxf(fmaxf(m0, m1), fmaxf(m2, m3));
    float numc = w * w * m;
    float denc = w;
    #pragma unroll
    for (int o = 32; o > 0; o >>= 1) {
        numc += __shfl_xor(numc, o);
        denc += __shfl_xor(denc, o);
    }
    if ((t & 63) == 0) { pn[t >> 6] = numc; pd[t >> 6] = denc; }
    __syncthreads();
    if (t == 0) {
        float sn = 0.f, sd = 0.f;
        #pragma unroll
        for (int wv = 0; wv < 6; wv++) { sn += pn[wv]; sd += pd[wv]; }
        atomicAdd(&accum[0], sn);
        atomicAdd(&accum[1], sd);
        __threadfence();
        unsigned int tk = atomicAdd((unsigned int*)accum + 2, 1u);
        if (tk == (unsigned int)(N - 1)) {          // last block: finalize
            float num = atomicAdd(&accum[0], 0.f);  // coherent read
            float den = atomicAdd(&accum[1], 0.f);
            out[0] = (den > 0.f) ? num / den : 0.f;
        }
    }
}

extern "C" void kernel_launch(void* const* d_in, const int* in_sizes, int n_in,
                              void* d_out, int out_size, void* d_ws, size_t ws_size,
                              hipStream_t stream) {
    const float* src = (const float*)d_in[0];
    const float* emb = (const float*)d_in[1];
    float* out = (float*)d_out;

    float* ws = (float*)d_ws;
    float* dsrc  = ws;                    // N*N  src distances
    float* demb  = dsrc + N * N;          // N*N  emb distances
    float* tsum  = demb + N * N;          // 144  per-tile src-distance sums
    float* accum = tsum + 144;            // [0]=num [1]=den [2]=ticket(uint)

    k_gram<<<288, 256, 0, stream>>>(src, emb, dsrc, demb, tsum, accum);
    k_main<<<N, N, 0, stream>>>(dsrc, demb, tsum, accum, out);
}